// Round 10
// baseline (227.478 us; speedup 1.0000x reference)
//
#include <hip/hip_runtime.h>
#include <math.h>

// Problem constants (B=1): S=4096, D=128, NHEADS=4, hd=32, N_COE=50, N_SCALES=4, THRE=5
//
// ws layout (floats):
//   eig   @ 0        (524288)
//   qkv   @ 524288   (1572864; only Q panel used, f32)
//   Oe    @ 2097152  (4*4096*128)
//   E     @ 4194304  (4*4*4096)
//   xsum  @ 4259840  (128)
//   coef  @ 4259968  (104; pad)
//   Khi_g @ 4260352  (262144 f = 524288 us)  [h][key][d] bf16 hi
//   Klo_g @ 4522496  (262144)                [h][key][d] bf16 lo
//   Vt_g  @ 4784640  (262144)                [h*32+d][key] bf16
//   eT0   @ 5046784  (128)      transposed weights [c][k]
//   eT    @ 5046912  (16384)
//   iT    @ 5063296  (49152)
//   oT    @ 5112448  (16384)
//   w1T   @ 5128832  (16384)
//   w2T   @ 5145216  (16384)
// total ~20.6 MB

#define KSPLIT 4

typedef __attribute__((ext_vector_type(8))) short short8;   // 8 bf16
typedef __attribute__((ext_vector_type(4))) short short4v;  // 4 bf16 (8B)
typedef __attribute__((ext_vector_type(4))) float f32x4;

__device__ inline unsigned short f2bf(float x) {            // RNE f32->bf16 bits
    unsigned u = __float_as_uint(x);
    return (unsigned short)((u + 0x7FFFu + ((u >> 16) & 1u)) >> 16);
}
__device__ inline float bf2f(unsigned short h) { return __uint_as_float(((unsigned)h) << 16); }

// ---------------- K0: weight transpose to [c][k] (enables float4 weight streams) ----------------
__global__ __launch_bounds__(256) void k_wprep(const float* __restrict__ eigW,
    const float* __restrict__ inW, const float* __restrict__ outW,
    const float* __restrict__ W1, const float* __restrict__ W2,
    float* __restrict__ eT0, float* __restrict__ eT, float* __restrict__ iT,
    float* __restrict__ oT, float* __restrict__ w1T, float* __restrict__ w2T)
{
    const int i = blockIdx.x * 256 + threadIdx.x;
    if (i < 16384) {
        const int j = i & 127, c = i >> 7;       // eT[c][j] = eigW[j+1][c]
        eT[c * 128 + j] = eigW[(j + 1) * 128 + c];
    } else if (i < 65536) {
        const int a = i - 16384;
        const int k = a & 127, c = a >> 7;       // c in [0,384)
        iT[c * 128 + k] = inW[k * 384 + c];
    } else if (i < 81920) {
        const int a = i - 65536; const int k = a & 127, c = a >> 7;
        oT[c * 128 + k] = outW[k * 128 + c];
    } else if (i < 98304) {
        const int a = i - 81920; const int k = a & 127, c = a >> 7;
        w1T[c * 128 + k] = W1[k * 128 + c];
    } else if (i < 114688) {
        const int a = i - 98304; const int k = a & 127, c = a >> 7;
        w2T[c * 128 + k] = W2[k * 128 + c];
    } else if (i < 114816) {
        eT0[i - 114688] = eigW[i - 114688];      // W row 0 (raw-e term)
    }
}

// ---------------- K1: fused sine-encoding + eig GEMM + LN1 + qkv GEMM ----------------
__global__ __launch_bounds__(256) void k_embed(const float* __restrict__ eve,
    const float* __restrict__ eT0, const float* __restrict__ eT, const float* __restrict__ ebias,
    const float* __restrict__ g, const float* __restrict__ b,
    const float* __restrict__ iT, const float* __restrict__ inb,
    float* __restrict__ eig, float* __restrict__ qkv, unsigned short* __restrict__ Khi_g,
    unsigned short* __restrict__ Klo_g, unsigned short* __restrict__ Vt_g)
{
    __shared__ __align__(16) float se[8][132];    // [0..63]=sin, [64..127]=cos, [128]=e
    __shared__ __align__(16) float x[8][128];     // eig rows
    __shared__ __align__(16) float xn[8][128];    // LN1 output
    __shared__ float red1[8][32];
    __shared__ float red2[8][32];
    __shared__ __align__(16) unsigned short vsh[128][8];
    const int t = threadIdx.x;
    const int r0 = blockIdx.x * 8;
    {   // Phase A: sin/cos features
        const int r = t >> 5, l = t & 31;
        const float e = eve[r0 + r];
        if (l == 0) se[r][128] = e;
        const float e100 = e * 100.0f;
        #pragma unroll
        for (int jj = 0; jj < 2; ++jj) {
            const int j = l * 2 + jj;
            const float div = __expf(-0.07195578415606394f * (float)(2 * j));
            const float pe = e100 * div;          // |pe| <= 200 rad
            se[r][j]      = __sinf(pe);
            se[r][64 + j] = __cosf(pe);
        }
    }
    __syncthreads();
    const int c = t & 127;
    const int rg = t >> 7;                        // rows rg+2i, i<4
    {   // Phase B: eig = eeig @ W + b, float4 weight stream
        float acc[4];
        const float w0 = eT0[c];
        #pragma unroll
        for (int i = 0; i < 4; ++i) acc[i] = se[rg + 2 * i][128] * w0;
        #pragma unroll 8
        for (int k = 0; k < 128; k += 4) {
            const float4 w = *(const float4*)&eT[c * 128 + k];
            #pragma unroll
            for (int i = 0; i < 4; ++i) {
                const float4 xv = *(const float4*)&se[rg + 2 * i][k];
                float a = acc[i];
                a = fmaf(xv.x, w.x, a);
                a = fmaf(xv.y, w.y, a);
                a = fmaf(xv.z, w.z, a);
                a = fmaf(xv.w, w.w, a);
                acc[i] = a;
            }
        }
        const float bb = ebias[c];
        #pragma unroll
        for (int i = 0; i < 4; ++i) {
            const float v = acc[i] + bb;
            x[rg + 2 * i][c] = v;
            eig[(r0 + rg + 2 * i) * 128 + c] = v;
        }
    }
    __syncthreads();
    {   // Phase C: LN1
        const int r = t >> 5, l = t & 31;
        float v[4];
        float s = 0.f, ss = 0.f;
        #pragma unroll
        for (int m = 0; m < 4; ++m) {
            const float xx = x[r][l + 32 * m];
            v[m] = xx; s += xx; ss += xx * xx;
        }
        red1[r][l] = s; red2[r][l] = ss;
        __syncthreads();
        for (int o = 16; o > 0; o >>= 1) {
            if (l < o) { red1[r][l] += red1[r][l + o]; red2[r][l] += red2[r][l + o]; }
            __syncthreads();
        }
        const float mean = red1[r][0] * (1.f / 128.f);
        const float var  = red2[r][0] * (1.f / 128.f) - mean * mean;
        const float inv  = 1.f / sqrtf(var + 1e-5f);
        #pragma unroll
        for (int m = 0; m < 4; ++m) {
            const int col = l + 32 * m;
            xn[r][col] = (v[m] - mean) * inv * g[col] + b[col];
        }
    }
    __syncthreads();
    {   // Phase D: qkv GEMM, 3 panels, float4 weight streams
        float acc[3][4];
        #pragma unroll
        for (int p = 0; p < 3; ++p) {
            const float bb = inb[p * 128 + c];
            #pragma unroll
            for (int i = 0; i < 4; ++i) acc[p][i] = bb;
        }
        #pragma unroll 4
        for (int k = 0; k < 128; k += 4) {
            float4 xv[4];
            #pragma unroll
            for (int i = 0; i < 4; ++i) xv[i] = *(const float4*)&xn[rg + 2 * i][k];
            #pragma unroll
            for (int p = 0; p < 3; ++p) {
                const float4 w = *(const float4*)&iT[(p * 128 + c) * 128 + k];
                #pragma unroll
                for (int i = 0; i < 4; ++i) {
                    float a = acc[p][i];
                    a = fmaf(xv[i].x, w.x, a);
                    a = fmaf(xv[i].y, w.y, a);
                    a = fmaf(xv[i].z, w.z, a);
                    a = fmaf(xv[i].w, w.w, a);
                    acc[p][i] = a;
                }
            }
        }
        // Q: f32
        #pragma unroll
        for (int i = 0; i < 4; ++i)
            qkv[(r0 + rg + 2 * i) * 384 + c] = acc[0][i];
        // K: bf16 hi/lo, [h][key][d]
        {
            const int h = c >> 5, d = c & 31;
            #pragma unroll
            for (int i = 0; i < 4; ++i) {
                const int row = r0 + rg + 2 * i;
                const float kv = acc[1][i];
                const unsigned short hb = f2bf(kv);
                Khi_g[((size_t)h * 4096 + row) * 32 + d] = hb;
                Klo_g[((size_t)h * 4096 + row) * 32 + d] = f2bf(kv - bf2f(hb));
            }
        }
        // V: bf16 via LDS transpose
        #pragma unroll
        for (int i = 0; i < 4; ++i)
            vsh[c][rg + 2 * i] = f2bf(acc[2][i]);
        __syncthreads();
        if (t < 128) {
            const uint4 vv = *(const uint4*)&vsh[t][0];
            *(uint4*)&Vt_g[(size_t)t * 4096 + r0] = vv;
        }
    }
}

// ---------------- K3: MFMA flash attention (no-max linear partials) ----------------
#define KSTR 40
#define VSTR 72
#define PSTR 72

__global__ __launch_bounds__(256) void k_attn(const float* __restrict__ qkv,
    const unsigned short* __restrict__ Khi_g, const unsigned short* __restrict__ Klo_g,
    const unsigned short* __restrict__ Vt_g,
    const int* __restrict__ sele, float* __restrict__ Oe, float* __restrict__ E)
{
    __shared__ __align__(16) unsigned short Khi[64 * KSTR];
    __shared__ __align__(16) unsigned short Klo[64 * KSTR];
    __shared__ __align__(16) unsigned short Vt[32 * VSTR];
    __shared__ __align__(16) unsigned short Pb[4][16 * PSTR];

    const int t = threadIdx.x;
    const int lane = t & 63;
    const int l = lane & 15;
    const int quad = lane >> 4;
    const int wv = __builtin_amdgcn_readfirstlane(t >> 6);
    const int qb = blockIdx.x;   // 64 q-blocks of 64
    const int h  = blockIdx.y;   // 4 heads
    const int ks = blockIdx.z;   // 4 key slots of 1024
    const int nk = sele[0];

    short8 qhi, qlo;
    {
        const float* __restrict__ qr = qkv + (size_t)(qb * 64 + wv * 16 + l) * 384 + h * 32 + quad * 8;
        const float4 a = *(const float4*)qr;
        const float4 b = *(const float4*)(qr + 4);
        const float sc = 0.17677669529663687f;   // 1/sqrt(32)
        float v[8] = {a.x * sc, a.y * sc, a.z * sc, a.w * sc, b.x * sc, b.y * sc, b.z * sc, b.w * sc};
        #pragma unroll
        for (int j = 0; j < 8; ++j) {
            const unsigned short hb = f2bf(v[j]);
            qhi[j] = (short)hb;
            qlo[j] = (short)f2bf(v[j] - bf2f(hb));
        }
    }
    f32x4 accO0 = {0.f, 0.f, 0.f, 0.f};
    f32x4 accO1 = {0.f, 0.f, 0.f, 0.f};
    float elane = 0.f;

    const int kk = t >> 2;                 // 0..63 key for K staging
    const int d0 = (t & 3) * 8;            // d-octet for K staging
    const int vd = t >> 3;                 // 0..31 d for V staging
    const int ko = (t & 7) * 8;            // key-octet for V staging

    for (int ch = 0; ch < 16; ++ch) {
        const int keybase = ks * 1024 + ch * 64;
        __syncthreads();
        {
            const uint4 kh16 = *(const uint4*)&Khi_g[((size_t)h * 4096 + keybase + kk) * 32 + d0];
            const uint4 kl16 = *(const uint4*)&Klo_g[((size_t)h * 4096 + keybase + kk) * 32 + d0];
            const uint4 vv16 = *(const uint4*)&Vt_g[((size_t)h * 32 + vd) * 4096 + keybase + ko];
            *(uint4*)&Khi[kk * KSTR + d0] = kh16;
            *(uint4*)&Klo[kk * KSTR + d0] = kl16;
            *(uint4*)&Vt[vd * VSTR + ko]  = vv16;
        }
        __syncthreads();
        unsigned short* __restrict__ Pw = Pb[wv];
        #pragma unroll
        for (int tile = 0; tile < 4; ++tile) {
            const int kl = tile * 16 + l;
            const short8 kh = *(const short8*)&Khi[kl * KSTR + quad * 8];
            const short8 kw = *(const short8*)&Klo[kl * KSTR + quad * 8];
            f32x4 S = {0.f, 0.f, 0.f, 0.f};
            S = __builtin_amdgcn_mfma_f32_16x16x32_bf16(kh, qhi, S, 0, 0, 0);
            S = __builtin_amdgcn_mfma_f32_16x16x32_bf16(kw, qhi, S, 0, 0, 0);
            S = __builtin_amdgcn_mfma_f32_16x16x32_bf16(kh, qlo, S, 0, 0, 0);
            const int kg0 = keybase + tile * 16 + quad * 4;
            short4v pw;
            #pragma unroll
            for (int r = 0; r < 4; ++r) {
                const float p = (kg0 + r < nk) ? __expf(S[r]) : 0.f;
                elane += p;
                pw[r] = (short)f2bf(p);
            }
            *(short4v*)&Pw[l * PSTR + tile * 16 + quad * 4] = pw;
        }
        #pragma unroll
        for (int step = 0; step < 2; ++step) {
            const short8 pa  = *(const short8*)&Pw[l * PSTR + step * 32 + quad * 8];
            const short8 vb0 = *(const short8*)&Vt[l * VSTR + step * 32 + quad * 8];
            const short8 vb1 = *(const short8*)&Vt[(16 + l) * VSTR + step * 32 + quad * 8];
            accO0 = __builtin_amdgcn_mfma_f32_16x16x32_bf16(pa, vb0, accO0, 0, 0, 0);
            accO1 = __builtin_amdgcn_mfma_f32_16x16x32_bf16(pa, vb1, accO1, 0, 0, 0);
        }
    }
    elane += __shfl_xor(elane, 16, 64);
    elane += __shfl_xor(elane, 32, 64);
    const int qrow0 = qb * 64 + wv * 16;
    if (lane < 16)
        E[((size_t)ks * 4 + h) * 4096 + qrow0 + l] = elane;
    #pragma unroll
    for (int r = 0; r < 4; ++r) {
        const size_t row = qrow0 + quad * 4 + r;
        Oe[((size_t)ks * 4096 + row) * 128 + h * 32 + l]      = accO0[r];
        Oe[((size_t)ks * 4096 + row) * 128 + h * 32 + 16 + l] = accO1[r];
    }
}

// ---------------- K4: fold Oe/E + out-proj + residual + LN2 + FFN + residual + column-sum ----------------
__global__ __launch_bounds__(256) void k_ffn(const float* __restrict__ eig,
    const float* __restrict__ Oe, const float* __restrict__ E,
    const float* __restrict__ oT, const float* __restrict__ outb,
    const float* __restrict__ lg, const float* __restrict__ lb,
    const float* __restrict__ w1T, const float* __restrict__ b1,
    const float* __restrict__ w2T, const float* __restrict__ b2,
    const int* __restrict__ sele, float* __restrict__ xsum)
{
    __shared__ __align__(16) float sA[8][128];
    __shared__ __align__(16) float x2[8][128];
    __shared__ __align__(16) float xn[8][128];
    __shared__ float red1[8][32];
    __shared__ float red2[8][32];
    __shared__ float sEr[8][4];
    __shared__ float colsum[2][128];
    const int t = threadIdx.x;
    const int r0 = blockIdx.x * 8;
    const int r = t >> 5, l = t & 31;
    if (l < 4) {
        float es = 0.f;
        #pragma unroll
        for (int ks = 0; ks < KSPLIT; ++ks)
            es += E[((size_t)ks * 4 + l) * 4096 + r0 + r];
        sEr[r][l] = 1.f / es;
    }
    __syncthreads();
    #pragma unroll
    for (int m = 0; m < 4; ++m) {
        const int col = l + 32 * m;
        float v = 0.f;
        #pragma unroll
        for (int ks = 0; ks < KSPLIT; ++ks)
            v += Oe[((size_t)ks * 4096 + r0 + r) * 128 + col];
        sA[r][col] = v * sEr[r][col >> 5];
    }
    __syncthreads();
    const int c = t & 127;
    const int rg = t >> 7;
    {   // out projection + residual
        float acc[4];
        const float bb = outb[c];
        #pragma unroll
        for (int i = 0; i < 4; ++i) acc[i] = bb;
        #pragma unroll 8
        for (int k = 0; k < 128; k += 4) {
            const float4 w = *(const float4*)&oT[c * 128 + k];
            #pragma unroll
            for (int i = 0; i < 4; ++i) {
                const float4 x = *(const float4*)&sA[rg + 2 * i][k];
                float a = acc[i];
                a = fmaf(x.x, w.x, a);
                a = fmaf(x.y, w.y, a);
                a = fmaf(x.z, w.z, a);
                a = fmaf(x.w, w.w, a);
                acc[i] = a;
            }
        }
        #pragma unroll
        for (int i = 0; i < 4; ++i)
            x2[rg + 2 * i][c] = eig[(r0 + rg + 2 * i) * 128 + c] + acc[i];
    }
    __syncthreads();
    {   // LN2
        float s = 0.f, ss = 0.f;
        float v[4];
        #pragma unroll
        for (int m = 0; m < 4; ++m) {
            const float x = x2[r][l + 32 * m];
            v[m] = x; s += x; ss += x * x;
        }
        red1[r][l] = s; red2[r][l] = ss;
        __syncthreads();
        for (int o = 16; o > 0; o >>= 1) {
            if (l < o) { red1[r][l] += red1[r][l + o]; red2[r][l] += red2[r][l + o]; }
            __syncthreads();
        }
        const float mean = red1[r][0] * (1.f / 128.f);
        const float var  = red2[r][0] * (1.f / 128.f) - mean * mean;
        const float inv  = 1.f / sqrtf(var + 1e-5f);
        #pragma unroll
        for (int m = 0; m < 4; ++m) {
            const int col = l + 32 * m;
            xn[r][col] = (v[m] - mean) * inv * lg[col] + lb[col];
        }
    }
    __syncthreads();
    {   // FFN1 + exact gelu -> sA
        float acc[4];
        const float bb = b1[c];
        #pragma unroll
        for (int i = 0; i < 4; ++i) acc[i] = bb;
        #pragma unroll 8
        for (int k = 0; k < 128; k += 4) {
            const float4 w = *(const float4*)&w1T[c * 128 + k];
            #pragma unroll
            for (int i = 0; i < 4; ++i) {
                const float4 x = *(const float4*)&xn[rg + 2 * i][k];
                float a = acc[i];
                a = fmaf(x.x, w.x, a);
                a = fmaf(x.y, w.y, a);
                a = fmaf(x.z, w.z, a);
                a = fmaf(x.w, w.w, a);
                acc[i] = a;
            }
        }
        __syncthreads();
        #pragma unroll
        for (int i = 0; i < 4; ++i) {
            const float x = acc[i];
            sA[rg + 2 * i][c] = 0.5f * x * (1.f + erff(x * 0.70710678118654752f));
        }
    }
    __syncthreads();
    {   // FFN2 + residual + masked column sum
        float acc[4];
        const float bb = b2[c];
        #pragma unroll
        for (int i = 0; i < 4; ++i) acc[i] = bb;
        #pragma unroll 8
        for (int k = 0; k < 128; k += 4) {
            const float4 w = *(const float4*)&w2T[c * 128 + k];
            #pragma unroll
            for (int i = 0; i < 4; ++i) {
                const float4 x = *(const float4*)&sA[rg + 2 * i][k];
                float a = acc[i];
                a = fmaf(x.x, w.x, a);
                a = fmaf(x.y, w.y, a);
                a = fmaf(x.z, w.z, a);
                a = fmaf(x.w, w.w, a);
                acc[i] = a;
            }
        }
        const int nsel = sele[0];
        float local = 0.f;
        #pragma unroll
        for (int i = 0; i < 4; ++i) {
            const float ef = x2[rg + 2 * i][c] + acc[i];
            if (r0 + rg + 2 * i < nsel) local += ef;
        }
        colsum[rg][c] = local;
    }
    __syncthreads();
    if (rg == 0) atomicAdd(&xsum[c], colsum[0][c] + colsum[1][c]);
}

// ---------------- K5: pooled coefficients ----------------
__global__ __launch_bounds__(128) void k_coef(const float* __restrict__ xsum,
    const float* __restrict__ dscW, const float* __restrict__ dscb,
    const float* __restrict__ dwvW, const float* __restrict__ dwvb,
    const float* __restrict__ dssW, const float* __restrict__ dssb,
    const int* __restrict__ len, const int* __restrict__ sele,
    float* __restrict__ coef)
{
    __shared__ float xs[128];
    __shared__ float csc[50], cwv[50];
    __shared__ float s2[2];
    const int t = threadIdx.x;
    xs[t] = xsum[t];
    __syncthreads();
    const float invl = 1.f / ((float)len[0] + 1e-8f);
    const float ns = (float)sele[0];
    if (t < 50) {
        float a = ns * dscb[t];
        #pragma unroll 8
        for (int k = 0; k < 128; ++k) a = fmaf(xs[k], dscW[k * 50 + t], a);
        a *= invl;
        csc[t] = 1.f / (1.f + expf(-a));
    } else if (t >= 64 && t < 114) {
        const int j = t - 64;
        float a = ns * dwvb[j];
        #pragma unroll 8
        for (int k = 0; k < 128; ++k) a = fmaf(xs[k], dwvW[k * 50 + j], a);
        a *= invl;
        cwv[j] = 1.f / (1.f + expf(-a));
    } else if (t >= 114 && t < 118) {
        const int j = t - 114;
        float a = ns * dssb[j];
        #pragma unroll 8
        for (int k = 0; k < 128; ++k) a = fmaf(xs[k], dssW[k * 4 + j], a);
        a *= invl;
        coef[100 + j] = (1.f / (1.f + expf(-a))) * 5.0f;  // THRE
    }
    __syncthreads();
    if (t == 0) { float s = 0.f; for (int i2 = 0; i2 < 50; ++i2) s += csc[i2]; s2[0] = s; }
    if (t == 1) { float s = 0.f; for (int i2 = 0; i2 < 50; ++i2) s += cwv[i2]; s2[1] = s; }
    __syncthreads();
    if (t < 50) {
        coef[t]      = csc[t] / (s2[0] + 1e-8f);
        coef[50 + t] = cwv[t] / (s2[1] + 1e-8f);
    }
}

// ---------------- K6: Chebyshev bases + combine + normalize ----------------
__global__ __launch_bounds__(256) void k_out(const float* __restrict__ eve,
    const float* __restrict__ coef, float* __restrict__ out)
{
    __shared__ float csc[50], cwv[50], cs[4];
    const int t = threadIdx.x;
    if (t < 50) csc[t] = coef[t];
    else if (t < 100) cwv[t - 50] = coef[t];
    else if (t < 104) cs[t - 100] = coef[t];
    __syncthreads();
    const int s = blockIdx.x * 256 + t;
    const float e = eve[s];
    float vals[5];
    {
        const float y = e - 1.f;
        float te = 1.f, to = y;
        float a = csc[0] * (0.5f * (1.f - to));
        const float y2 = 2.f * y;
        for (int i = 1; i < 50; ++i) {
            te = fmaf(y2, to, -te);
            to = fmaf(y2, te, -to);
            a = fmaf(csc[i], 0.5f * (1.f - to), a);
        }
        vals[0] = a;
    }
    #pragma unroll
    for (int j = 0; j < 4; ++j) {
        float f = e * cs[j];
        if (f > 2.f) f = 0.f;
        const float y = f - 1.f;
        float te = 1.f, to = y;
        float a = cwv[0] * (0.5f * (1.f - te));
        const float y2 = 2.f * y;
        for (int i = 1; i < 50; ++i) {
            te = fmaf(y2, to, -te);
            to = fmaf(y2, te, -to);
            a = fmaf(cwv[i], 0.5f * (1.f - te), a);
        }
        vals[1 + j] = a;
    }
    float n2 = 0.f;
    #pragma unroll
    for (int k = 0; k < 5; ++k) n2 += vals[k] * vals[k];
    const float invn = 1.f / (sqrtf(n2) + 1e-8f);
    #pragma unroll
    for (int k = 0; k < 5; ++k) out[s * 5 + k] = vals[k] * invn;
}

extern "C" void kernel_launch(void* const* d_in, const int* in_sizes, int n_in,
                              void* d_out, int out_size, void* d_ws, size_t ws_size,
                              hipStream_t stream) {
    const float* eve  = (const float*)d_in[0];
    const int*   len  = (const int*)d_in[1];
    const int*   sele = (const int*)d_in[2];
    const float* eigW = (const float*)d_in[3];
    const float* eigB = (const float*)d_in[4];
    const float* mlg  = (const float*)d_in[5];
    const float* mlb  = (const float*)d_in[6];
    const float* inW  = (const float*)d_in[7];
    const float* inb  = (const float*)d_in[8];
    const float* outW = (const float*)d_in[9];
    const float* outb = (const float*)d_in[10];
    const float* flg  = (const float*)d_in[11];
    const float* flb  = (const float*)d_in[12];
    const float* W1   = (const float*)d_in[13];
    const float* b1   = (const float*)d_in[14];
    const float* W2   = (const float*)d_in[15];
    const float* b2   = (const float*)d_in[16];
    const float* dscW = (const float*)d_in[17];
    const float* dscb = (const float*)d_in[18];
    const float* dwvW = (const float*)d_in[19];
    const float* dwvb = (const float*)d_in[20];
    const float* dssW = (const float*)d_in[21];
    const float* dssb = (const float*)d_in[22];

    float* ws   = (float*)d_ws;
    float* eig  = ws;
    float* qkv  = ws + 524288;
    float* Oe   = ws + 2097152;
    float* E    = ws + 4194304;
    float* xsum = ws + 4259840;
    float* coef = ws + 4259968;
    unsigned short* Khi_g = (unsigned short*)(ws + 4260352);
    unsigned short* Klo_g = (unsigned short*)(ws + 4522496);
    unsigned short* Vt_g  = (unsigned short*)(ws + 4784640);
    float* eT0  = ws + 5046784;
    float* eT   = ws + 5046912;
    float* iT   = ws + 5063296;
    float* oT   = ws + 5112448;
    float* w1T  = ws + 5128832;
    float* w2T  = ws + 5145216;
    float* out  = (float*)d_out;

    hipMemsetAsync(xsum, 0, 128 * sizeof(float), stream);
    k_wprep<<<449, 256, 0, stream>>>(eigW, inW, outW, W1, W2, eT0, eT, iT, oT, w1T, w2T);
    k_embed<<<512, 256, 0, stream>>>(eve, eT0, eT, eigB, mlg, mlb, iT, inb,
                                     eig, qkv, Khi_g, Klo_g, Vt_g);
    k_attn <<<dim3(64, 4, KSPLIT), 256, 0, stream>>>(qkv, Khi_g, Klo_g, Vt_g, sele, Oe, E);
    k_ffn  <<<512, 256, 0, stream>>>(eig, Oe, E, oT, outb, flg, flb, w1T, b1, w2T, b2, sele, xsum);
    k_coef <<<1, 128, 0, stream>>>(xsum, dscW, dscb, dwvW, dwvb, dssW, dssb, len, sele, coef);
    k_out  <<<16, 256, 0, stream>>>(eve, coef, out);
}